// Round 5
// baseline (594.625 us; speedup 1.0000x reference)
//
#include <hip/hip_runtime.h>

#define B_   4
#define S_   2048
#define D_   1024
#define DFF_ 4096

typedef __attribute__((ext_vector_type(8))) short short8;
typedef __attribute__((ext_vector_type(4))) float floatx4;

__device__ __forceinline__ unsigned short f2b(float f) {
    unsigned int u = __float_as_uint(f);
    unsigned int r = (u + 0x7fffu + ((u >> 16) & 1u)) >> 16;
    return (unsigned short)r;
}
__device__ __forceinline__ float b2f(unsigned short u) {
    return __uint_as_float((unsigned int)u << 16);
}

// XCD-aware swizzle: blocks sharing an A row-tile (same by) land on one XCD.
__device__ __forceinline__ void swizzle_xy(int gx, int gy, int& bx, int& by) {
    if ((gy & 7) == 0) {
        const int linear = by * gx + bx;
        const int xcd = linear & 7;
        const int slot = linear >> 3;
        const int r = slot / gx;
        by = xcd * (gy >> 3) + r;
        bx = slot - r * gx;
    }
}

#define GLL(src, dst) __builtin_amdgcn_global_load_lds( \
    (const __attribute__((address_space(1))) void*)(src), \
    (__attribute__((address_space(3))) void*)(dst), 16, 0, 0)

__device__ __forceinline__ void barrier_mem() {
    asm volatile("" ::: "memory");
    __builtin_amdgcn_s_barrier();
    asm volatile("" ::: "memory");
}

// ---------------------------------------------------------------------------
// GEMM core: 256x256 tile, BK=64, 512 threads / 8 waves (2M x 4N, 128x64 each).
// m201-faithful 8-phase schedule, 8 uniform phases per 2 K-tiles. Each phase:
//   {12 ds_read_b128 (one C-quadrant x K=64); stage ONE half-tile (2 GLL);
//    lgkmcnt(8); barrier; lgkmcnt(0); setprio(1); 16 MFMA; setprio(0);
//    [vmcnt(4) at P4/P8]; barrier}
// Quadrant (mh,np) of wave tile 128x64: rows mh*64+(0..63), cols np*32+(0..31).
// LDS row remap groups rows by quadrant so half-tiles = quadrant read-sets:
//   A: LDSrow = mh*128 + wm*64 + (arow&63)   (Aa = LDS rows 0-127: arow 0-63,128-191)
//   B: LDSrow = np*128 + wn*32 + (brow&31)   (Ba = LDS rows 0-127: np=0 quarters)
// Stage rotation per iteration (compute t=buf0 P1-4, t+1=buf1 P5-8):
//   P1:(t+1).Ab->buf1  P2:(t+1).Bb->buf1  P3:(t+2).Aa->buf0  P4:(t+2).Ba->buf0
//   P5:(t+2).Ab->buf0  P6:(t+2).Bb->buf0  P7:(t+3).Aa->buf1  P8:(t+3).Ba->buf1
// WAR: each target freed >=1 barrier before its rewrite (quadrant reads:
//   Aa@P1P2, Ba@P1P3, Ab@P3P4, Bb@P2P4 per buffer — all verified).
// RAW: vmcnt(4) at P4-end leaves only P3,P4 stages in flight => P1,P2(i) and
//   P7,P8(i-1) landed before P5 reads buf1; vmcnt(4) at P8-end leaves P7,P8
//   => P3..P6(i) landed before next P1 reads buf0. Leads 4-6 phases >> HBM lat.
// 16B-granule XOR swizzle slot = g ^ (LDSrow&7) via pre-swizzled global source
// column (LDS dest stays linear for global_load_lds); ds_read applies same XOR.
// ---------------------------------------------------------------------------
__device__ __forceinline__ void gemm_core256sq(
    const unsigned short* __restrict__ A,
    const unsigned short* __restrict__ Bt,
    int ldA, int ldB, int K, int m0, int n0,
    unsigned short* __restrict__ lds,   // 65536 shorts: A0|A1|B0|B1 (16384 each)
    floatx4 acc[8][4])
{
    const int tid  = threadIdx.x;   // 0..511
    const int lane = tid & 63;
    const int wave = tid >> 6;      // 0..7
    const int wm   = wave >> 2;     // 0..1 (M half of tile)
    const int wn   = wave & 3;      // 0..3 (N quarter of tile)

    // ---- staging setup: thread covers (chunk row ra, k-granule pg); source
    //      col pre-swizzled so linear LDS dest realizes slot = g ^ (row&7).
    const int ra = tid >> 3;        // 0..63 (row within 64-row GLL chunk)
    const int pg = tid & 7;
    const int cg = (pg ^ (ra & 7)) * 8;
    const unsigned short* gA = A + (long long)(m0 + ra) * ldA + cg;
    const int brow = ((ra >> 5) << 6) + (ra & 31);   // {0-31,64-95} base rows
    const unsigned short* gB = Bt + (long long)(n0 + brow) * ldB + cg;
    const long long r64A = 64LL * ldA;
    const long long r32B = 32LL * ldB;
    unsigned short* const dA = lds + wave * 512;           // + buf*16384 + chunk
    unsigned short* const dB = lds + 32768 + wave * 512;

    // ---- fragment read setup (16x16x32 bf16)
    const int fr = lane & 15;
    const int q  = lane >> 4;
    const int sw0 = (q ^ (fr & 7)) * 8;       // k-slice 0 swizzled granule off
    const int sw1 = sw0 ^ 32;                 // k-slice 1
    const unsigned short* const pA0 = lds + (wm * 64 + fr) * 64;
    const unsigned short* const pB0 = lds + 32768 + (wn * 32 + fr) * 64;

// half-tile stages: 2 GLLs each, 64-row chunks, LDS linear per chunk
#define STG_Aa(buf, kk) do { \
    GLL(gA + (kk),            dA + (buf) * 16384 + 0); \
    GLL(gA + 2 * r64A + (kk), dA + (buf) * 16384 + 4096); } while (0)
#define STG_Ab(buf, kk) do { \
    GLL(gA + r64A + (kk),     dA + (buf) * 16384 + 8192); \
    GLL(gA + 3 * r64A + (kk), dA + (buf) * 16384 + 12288); } while (0)
#define STG_Ba(buf, kk) do { \
    GLL(gB + (kk),            dB + (buf) * 16384 + 0); \
    GLL(gB + 4 * r32B + (kk), dB + (buf) * 16384 + 4096); } while (0)
#define STG_Bb(buf, kk) do { \
    GLL(gB + r32B + (kk),     dB + (buf) * 16384 + 8192); \
    GLL(gB + 5 * r32B + (kk), dB + (buf) * 16384 + 12288); } while (0)
#define VMC(n)  asm volatile("s_waitcnt vmcnt(" #n ")" ::: "memory")

#define PHASE(bufo, mh, np, STAGE, GATE) do { \
    short8 af[4][2], bf[2][2]; \
    _Pragma("unroll") for (int _i = 0; _i < 4; ++_i) { \
        af[_i][0] = *(const short8*)(pA0 + (bufo) + (mh) * 8192 + _i * 1024 + sw0); \
        af[_i][1] = *(const short8*)(pA0 + (bufo) + (mh) * 8192 + _i * 1024 + sw1); } \
    _Pragma("unroll") for (int _j = 0; _j < 2; ++_j) { \
        bf[_j][0] = *(const short8*)(pB0 + (bufo) + (np) * 8192 + _j * 1024 + sw0); \
        bf[_j][1] = *(const short8*)(pB0 + (bufo) + (np) * 8192 + _j * 1024 + sw1); } \
    STAGE; \
    asm volatile("s_waitcnt lgkmcnt(8)" ::: "memory"); \
    barrier_mem(); \
    asm volatile("s_waitcnt lgkmcnt(0)" ::: "memory"); \
    __builtin_amdgcn_s_setprio(1); \
    _Pragma("unroll") for (int _i = 0; _i < 4; ++_i) \
    _Pragma("unroll") for (int _j = 0; _j < 2; ++_j) \
    _Pragma("unroll") for (int _h = 0; _h < 2; ++_h) \
        acc[(mh) * 4 + _i][(np) * 2 + _j] = __builtin_amdgcn_mfma_f32_16x16x32_bf16( \
            af[_i][_h], bf[_j][_h], acc[(mh) * 4 + _i][(np) * 2 + _j], 0, 0, 0); \
    __builtin_amdgcn_s_setprio(0); \
    GATE; \
    barrier_mem(); \
} while (0)

    const int NT = K >> 6;                       // K-tiles; always even, >= 8
    const long long kcap = (long long)K - 64;

    // prologue: tile0 full -> buf0; tile1 Aa,Ba -> buf1 (Ab,Bb staged P1,P2)
    STG_Aa(0, 0); STG_Ba(0, 0); STG_Ab(0, 0); STG_Bb(0, 0);
    STG_Aa(1, 64); STG_Ba(1, 64);
    VMC(4);                 // tile0's 8 GLLs landed; tile1 Aa,Ba in flight
    barrier_mem();

    for (int t = 0; t < NT; t += 2) {           // tile t -> buf0, t+1 -> buf1
        const long long k1 = (long long)(t + 1) * 64;   // always valid
        long long k2 = (long long)(t + 2) * 64; if (k2 > kcap) k2 = kcap;
        long long k3 = (long long)(t + 3) * 64; if (k3 > kcap) k3 = kcap;

        PHASE(0,     0, 0, STG_Ab(1, k1), ((void)0));
        PHASE(0,     0, 1, STG_Bb(1, k1), ((void)0));
        PHASE(0,     1, 0, STG_Aa(0, k2), ((void)0));
        PHASE(0,     1, 1, STG_Ba(0, k2), VMC(4));
        PHASE(16384, 0, 0, STG_Ab(0, k2), ((void)0));
        PHASE(16384, 0, 1, STG_Bb(0, k2), ((void)0));
        PHASE(16384, 1, 0, STG_Aa(1, k3), ((void)0));
        PHASE(16384, 1, 1, STG_Ba(1, k3), VMC(4));
    }
    VMC(0);   // drain redundant epilogue stages before LDS goes out of scope

#undef STG_Aa
#undef STG_Ab
#undef STG_Ba
#undef STG_Bb
#undef PHASE
#undef VMC
}

// ---------------------------------------------------------------------------
__global__ __launch_bounds__(256) void cast_bf16_kernel(
    const float4* __restrict__ src, ushort4* __restrict__ dst, int n4)
{
    int i = blockIdx.x * 256 + threadIdx.x;
    if (i < n4) {
        float4 f = src[i];
        ushort4 u;
        u.x = f2b(f.x); u.y = f2b(f.y); u.z = f2b(f.z); u.w = f2b(f.w);
        dst[i] = u;
    }
}

// ---------------------------------------------------------------------------
__global__ __launch_bounds__(256) void transpose_cast_kernel(
    const float* __restrict__ W, unsigned short* __restrict__ Wt, int K, int N)
{
    __shared__ float tile[32][33];
    const int tx = threadIdx.x;
    const int ty = threadIdx.y;
    const int bx = blockIdx.x * 32;
    const int by = blockIdx.y * 32;
#pragma unroll
    for (int j = 0; j < 32; j += 8)
        tile[ty + j][tx] = W[(long long)(by + ty + j) * N + bx + tx];
    __syncthreads();
#pragma unroll
    for (int j = 0; j < 32; j += 8)
        Wt[(long long)(bx + ty + j) * K + by + tx] = f2b(tile[tx][ty + j]);
}

// ---------------------------------------------------------------------------
// bf16 transpose: Vb [B][S][D] -> Vt [B][D][S]. 64x64 LDS tiles, ushort4 IO.
// ---------------------------------------------------------------------------
__global__ __launch_bounds__(256) void vtrans_kernel(
    const unsigned short* __restrict__ Vb, unsigned short* __restrict__ Vt)
{
    __shared__ unsigned short tile[64][68];
    const int b  = blockIdx.z;
    const int s0 = blockIdx.y * 64;
    const int d0 = blockIdx.x * 64;
    const int tx = threadIdx.x & 15;
    const int ty = threadIdx.x >> 4;

    const unsigned short* src = Vb + ((long long)b * S_ + s0) * D_ + d0;
#pragma unroll
    for (int j = 0; j < 4; j++) {
        const int s = j * 16 + ty;
        ushort4 v = *(const ushort4*)(src + (long long)s * D_ + tx * 4);
        tile[tx * 4 + 0][s] = v.x;
        tile[tx * 4 + 1][s] = v.y;
        tile[tx * 4 + 2][s] = v.z;
        tile[tx * 4 + 3][s] = v.w;
    }
    __syncthreads();
    unsigned short* dst = Vt + ((long long)b * D_ + d0) * S_ + s0;
#pragma unroll
    for (int j = 0; j < 4; j++) {
        const int d = j * 16 + ty;
        ushort4 v;
        v.x = tile[d][tx * 4 + 0];
        v.y = tile[d][tx * 4 + 1];
        v.z = tile[d][tx * 4 + 2];
        v.w = tile[d][tx * 4 + 3];
        *(ushort4*)(dst + (long long)d * S_ + tx * 4) = v;
    }
}

// ---------------------------------------------------------------------------
// GEMM: C = act(scale * A @ Bt^T + bias), batched via z. 256x256 tile.
// ---------------------------------------------------------------------------
template <int OUT_BF16, int ACT_LEAKY, int HAS_BIAS>
__global__ __launch_bounds__(512, 2) void gemm_bt(
    const unsigned short* __restrict__ A,
    const unsigned short* __restrict__ Bt,
    void* __restrict__ Cptr,
    const float* __restrict__ bias,
    int M, int N, int K, float scale,
    long long sA, long long sB, long long sC)
{
    __shared__ unsigned short lds[65536];

    const int lane = threadIdx.x & 63;
    const int wave = threadIdx.x >> 6;
    const int z    = blockIdx.z;

    int bx = blockIdx.x, by = blockIdx.y;
    swizzle_xy(gridDim.x, gridDim.y, bx, by);
    const int m0 = by * 256;
    const int n0 = bx * 256;

    floatx4 acc[8][4];
#pragma unroll
    for (int i = 0; i < 8; i++)
#pragma unroll
        for (int j = 0; j < 4; j++) acc[i][j] = floatx4{0.f, 0.f, 0.f, 0.f};

    gemm_core256sq(A + (long long)z * sA, Bt + (long long)z * sB,
                   K, K, K, m0, n0, lds, acc);

    const int wr = (wave >> 2) * 128;
    const int wc = (wave & 3) * 64;
    const int cr = (lane >> 4) * 4;
    const int cc = lane & 15;
    float* Cf = (float*)Cptr;
    unsigned short* Cb = (unsigned short*)Cptr;

#pragma unroll
    for (int mi = 0; mi < 8; mi++) {
#pragma unroll
        for (int ni = 0; ni < 4; ni++) {
            const int col = n0 + wc + ni * 16 + cc;
            const float bv = HAS_BIAS ? bias[col] : 0.0f;
#pragma unroll
            for (int r = 0; r < 4; r++) {
                const int row = m0 + wr + mi * 16 + cr + r;
                float v = acc[mi][ni][r] * scale + bv;
                if (ACT_LEAKY) v = (v > 0.0f) ? v : 0.01f * v;
                const long long idx = (long long)z * sC + (long long)row * N + col;
                if (OUT_BF16) Cb[idx] = f2b(v); else Cf[idx] = v;
            }
        }
    }
}

// ---------------------------------------------------------------------------
// Split-K GEMM, 256x256 tile: blockIdx.z = b * NK + ks;
// partial P[(ks*nb + b)][M][N] stored bf16.
// ---------------------------------------------------------------------------
template <int NK>
__global__ __launch_bounds__(512, 2) void gemm_bt_sk(
    const unsigned short* __restrict__ A,
    const unsigned short* __restrict__ Bt,
    unsigned short* __restrict__ P,
    int M, int N, int Kslice, int ldA, int ldB,
    long long sA, long long sB)
{
    __shared__ unsigned short lds[65536];

    const int lane = threadIdx.x & 63;
    const int wave = threadIdx.x >> 6;
    const int z    = blockIdx.z;
    const int ks   = z % NK;
    const int b    = z / NK;
    const int nb   = gridDim.z / NK;

    int bx = blockIdx.x, by = blockIdx.y;
    swizzle_xy(gridDim.x, gridDim.y, bx, by);
    const int m0 = by * 256;
    const int n0 = bx * 256;

    floatx4 acc[8][4];
#pragma unroll
    for (int i = 0; i < 8; i++)
#pragma unroll
        for (int j = 0; j < 4; j++) acc[i][j] = floatx4{0.f, 0.f, 0.f, 0.f};

    gemm_core256sq(A + (long long)b * sA + (long long)ks * Kslice,
                   Bt + (long long)b * sB + (long long)ks * Kslice,
                   ldA, ldB, Kslice, m0, n0, lds, acc);

    const long long pbase = ((long long)ks * nb + b) * (long long)M * N;

    const int wr = (wave >> 2) * 128;
    const int wc = (wave & 3) * 64;
    const int cr = (lane >> 4) * 4;
    const int cc = lane & 15;

#pragma unroll
    for (int mi = 0; mi < 8; mi++) {
#pragma unroll
        for (int ni = 0; ni < 4; ni++) {
            const int col = n0 + wc + ni * 16 + cc;
#pragma unroll
            for (int r = 0; r < 4; r++) {
                const int row = m0 + wr + mi * 16 + cr + r;
                P[pbase + (long long)row * N + col] = f2b(acc[mi][ni][r]);
            }
        }
    }
}

// ---------------------------------------------------------------------------
// Fused QKV GEMM, 256x256 tile: A[8192,1024] @ Wqkvt[3072,1024]^T
// All three segments write coalesced [row][c]; V transposed separately.
// ---------------------------------------------------------------------------
__global__ __launch_bounds__(512, 2) void gemm_qkv(
    const unsigned short* __restrict__ A,
    const unsigned short* __restrict__ Bt,
    unsigned short* __restrict__ Qb,
    unsigned short* __restrict__ Kb,
    unsigned short* __restrict__ Vb,
    const float* __restrict__ bq,
    const float* __restrict__ bk,
    const float* __restrict__ bv)
{
    __shared__ unsigned short lds[65536];

    const int lane = threadIdx.x & 63;
    const int wave = threadIdx.x >> 6;

    int bx = blockIdx.x, by = blockIdx.y;
    swizzle_xy(gridDim.x, gridDim.y, bx, by);
    const int m0 = by * 256;
    const int n0 = bx * 256;

    floatx4 acc[8][4];
#pragma unroll
    for (int i = 0; i < 8; i++)
#pragma unroll
        for (int j = 0; j < 4; j++) acc[i][j] = floatx4{0.f, 0.f, 0.f, 0.f};

    gemm_core256sq(A, Bt, D_, D_, D_, m0, n0, lds, acc);

    const int wr = (wave >> 2) * 128;
    const int wc = (wave & 3) * 64;
    const int cr = (lane >> 4) * 4;
    const int cc = lane & 15;

#pragma unroll
    for (int mi = 0; mi < 8; mi++) {
#pragma unroll
        for (int ni = 0; ni < 4; ni++) {
            const int col = n0 + wc + ni * 16 + cc;
            const int seg = col >> 10;
            const int c = col & 1023;
            const float* bp = (seg == 0) ? bq : ((seg == 1) ? bk : bv);
            unsigned short* dp = (seg == 0) ? Qb : ((seg == 1) ? Kb : Vb);
            const float bval = bp[c];
#pragma unroll
            for (int r = 0; r < 4; r++) {
                const int row = m0 + wr + mi * 16 + cr + r;
                dp[(long long)row * D_ + c] = f2b(acc[mi][ni][r] + bval);
            }
        }
    }
}

// ---------------------------------------------------------------------------
// AV reduce: bf16 out = p0 + p1 (bf16 partials)
// ---------------------------------------------------------------------------
__global__ __launch_bounds__(256) void avred_kernel(
    const ushort4* __restrict__ p0, const ushort4* __restrict__ p1,
    ushort4* __restrict__ dst, int n4)
{
    int i = blockIdx.x * 256 + threadIdx.x;
    if (i < n4) {
        ushort4 a = p0[i], b = p1[i];
        ushort4 u;
        u.x = f2b(b2f(a.x) + b2f(b.x)); u.y = f2b(b2f(a.y) + b2f(b.y));
        u.z = f2b(b2f(a.z) + b2f(b.z)); u.w = f2b(b2f(a.w) + b2f(b.w));
        dst[i] = u;
    }
}

// ---------------------------------------------------------------------------
// Fused split-K reduce + bias + residual + LayerNorm (bf16 partials).
// ---------------------------------------------------------------------------
template <int HAS_OUTB>
__global__ __launch_bounds__(256) void ln_red_kernel(
    const unsigned short* __restrict__ p0, const unsigned short* __restrict__ p1,
    const float* __restrict__ resid, const float* __restrict__ bias,
    const float* __restrict__ g, const float* __restrict__ b,
    float* __restrict__ out_f, unsigned short* __restrict__ out_b)
{
    __shared__ float red[8];
    const long long row = blockIdx.x;
    const int tid = threadIdx.x;
    const ushort4 a0 = ((const ushort4*)(p0 + row * D_))[tid];
    const ushort4 a1 = ((const ushort4*)(p1 + row * D_))[tid];
    const float4 rv = ((const float4*)(resid + row * D_))[tid];
    const float4 bi = ((const float4*)bias)[tid];
    float v0 = b2f(a0.x) + b2f(a1.x) + bi.x + rv.x;
    float v1 = b2f(a0.y) + b2f(a1.y) + bi.y + rv.y;
    float v2 = b2f(a0.z) + b2f(a1.z) + bi.z + rv.z;
    float v3 = b2f(a0.w) + b2f(a1.w) + bi.w + rv.w;

    float s = v0 + v1 + v2 + v3;
#pragma unroll
    for (int o = 32; o > 0; o >>= 1) s += __shfl_xor(s, o);
    if ((tid & 63) == 0) red[tid >> 6] = s;
    __syncthreads();
    const float mean = (red[0] + red[1] + red[2] + red[3]) * (1.0f / D_);

    const float d0 = v0 - mean, d1 = v1 - mean, d2 = v2 - mean, d3 = v3 - mean;
    float qv = d0 * d0 + d1 * d1 + d2 * d2 + d3 * d3;
#pragma unroll
    for (int o = 32; o > 0; o >>= 1) qv += __shfl_xor(qv, o);
    if ((tid & 63) == 0) red[4 + (tid >> 6)] = qv;
    __syncthreads();
    const float var = (red[4] + red[5] + red[6] + red[7]) * (1.0f / D_);
    const float inv = rsqrtf(var + 1e-6f);

    const float4 gv = ((const float4*)g)[tid];
    const float4 bv = ((const float4*)b)[tid];
    const float o0 = d0 * inv * gv.x + bv.x;
    const float o1 = d1 * inv * gv.y + bv.y;
    const float o2 = d2 * inv * gv.z + bv.z;
    const float o3 = d3 * inv * gv.w + bv.w;

    ((float4*)(out_f + row * D_))[tid] = float4{o0, o1, o2, o3};
    if (HAS_OUTB) {
        ushort4 u; u.x = f2b(o0); u.y = f2b(o1); u.z = f2b(o2); u.w = f2b(o3);
        ((ushort4*)(out_b + row * D_))[tid] = u;
    }
}

// ---------------------------------------------------------------------------
// softmax over rows of bf16 scores [B*S, S] + fp32 intensity -> bf16 attn
// ---------------------------------------------------------------------------
__global__ __launch_bounds__(256) void softmax_bias_kernel(
    const unsigned short* __restrict__ scores, const float* __restrict__ intensity,
    unsigned short* __restrict__ attn)
{
    __shared__ float red[8];
    const long long row = blockIdx.x;
    const int tid = threadIdx.x;
    const ushort4* s4 = (const ushort4*)(scores + row * S_);
    const float4* i4 = (const float4*)(intensity + row * S_);
    ushort4* dst = (ushort4*)(attn + row * S_);

    float vv[8];
    {
        ushort4 a = s4[tid], b = s4[tid + 256];
        vv[0] = b2f(a.x); vv[1] = b2f(a.y); vv[2] = b2f(a.z); vv[3] = b2f(a.w);
        vv[4] = b2f(b.x); vv[5] = b2f(b.y); vv[6] = b2f(b.z); vv[7] = b2f(b.w);
    }

    float mx = vv[0];
#pragma unroll
    for (int i = 1; i < 8; i++) mx = fmaxf(mx, vv[i]);
#pragma unroll
    for (int o = 32; o > 0; o >>= 1) mx = fmaxf(mx, __shfl_xor(mx, o));
    if ((tid & 63) == 0) red[tid >> 6] = mx;
    __syncthreads();
    mx = fmaxf(fmaxf(red[0], red[1]), fmaxf(red[2], red[3]));

    float e[8];
    float sum = 0.f;
#pragma unroll
    for (int i = 0; i < 8; i++) { e[i] = __expf(vv[i] - mx); sum += e[i]; }
#pragma unroll
    for (int o = 32; o > 0; o >>= 1) sum += __shfl_xor(sum, o);
    if ((tid & 63) == 0) red[4 + (tid >> 6)] = sum;
    __syncthreads();
    sum = red[4] + red[5] + red[6] + red[7];
    const float rs = 1.0f / sum;

#pragma unroll
    for (int i = 0; i < 2; i++) {
        float4 iv = i4[tid + 256 * i];
        ushort4 o;
        o.x = f2b(e[4 * i + 0] * rs + iv.x);
        o.y = f2b(e[4 * i + 1] * rs + iv.y);
        o.z = f2b(e[4 * i + 2] * rs + iv.z);
        o.w = f2b(e[4 * i + 3] * rs + iv.w);
        dst[tid + 256 * i] = o;
    }
}

// ---------------------------------------------------------------------------
extern "C" void kernel_launch(void* const* d_in, const int* in_sizes, int n_in,
                              void* d_out, int out_size, void* d_ws, size_t ws_size,
                              hipStream_t stream)
{
    const float* X   = (const float*)d_in[0];
    const float* inten = (const float*)d_in[1];
    const float* Wq  = (const float*)d_in[2];
    const float* bq  = (const float*)d_in[3];
    const float* Wk  = (const float*)d_in[4];
    const float* bk  = (const float*)d_in[5];
    const float* Wv  = (const float*)d_in[6];
    const float* bv  = (const float*)d_in[7];
    const float* Wo  = (const float*)d_in[8];
    const float* bo  = (const float*)d_in[9];
    const float* W1  = (const float*)d_in[10];
    const float* b1  = (const float*)d_in[11];
    const float* W2  = (const float*)d_in[12];
    const float* b2  = (const float*)d_in[13];
    const float* g1  = (const float*)d_in[14];
    const float* be1 = (const float*)d_in[15];
    const float* g2  = (const float*)d_in[16];
    const float* be2 = (const float*)d_in[17];
    float* out = (float*)d_out;

    char* ws = (char*)d_ws;
    const size_t MB = 1ull << 20;
    // timeline-aliased layout, peak 184 MB:
    unsigned short* Xb   = (unsigned short*)(ws + 0);        // 16MB; dead after QKV
    unsigned short* Wqkv = (unsigned short*)(ws + 16 * MB);  // 6MB
    unsigned short* Wot  = (unsigned short*)(ws + 22 * MB);  // 2MB
    unsigned short* W1t  = (unsigned short*)(ws + 24 * MB);  // 8MB
    unsigned short* W2t  = (unsigned short*)(ws + 32 * MB);  // 8MB
    unsigned short* Qb   = (unsigned short*)(ws + 40 * MB);  // 16MB; dead after scores
    unsigned short* Kb   = (unsigned short*)(ws + 56 * MB);  // 16MB; dead after scores
    unsigned short* Vt   = (unsigned short*)(ws + 72 * MB);  // 16MB; dead after attnV
    unsigned short* Sc   = (unsigned short*)(ws + 88 * MB);  // 32MB bf16; dead after softmax
    unsigned short* Vb   = (unsigned short*)(ws + 152 * MB); // 16MB; dead after vtrans
    unsigned short* At   = (unsigned short*)(ws + 152 * MB); // 32MB (after Vb dead); dead after AV
    unsigned short* AVp  = (unsigned short*)(ws + 88 * MB);  // 2x16MB bf16 (reuse Sc)
    unsigned short* AVb  = (unsigned short*)(ws + 0);        // 16MB (reuse Xb)
    unsigned short* Op   = (unsigned short*)(ws + 152 * MB); // 2x16MB bf16 (reuse At)
    float*          Hf   = (float*)(ws + 40 * MB);           // 32MB (reuse Qb+Kb)
    unsigned short* Hb   = (unsigned short*)(ws + 72 * MB);  // 16MB (reuse Vt)
    unsigned short* F1   = (unsigned short*)(ws + 88 * MB);  // 64MB (reuse AVp + free)
    unsigned short* Fp   = (unsigned short*)(ws + 152 * MB); // 2x16MB bf16 (reuse Op)

    const dim3 blk(256);
    const dim3 blk512(512);
    const dim3 tblk(32, 8);
    const long long MN_d = (long long)B_ * S_ * D_;

    // casts / weight transposes
    cast_bf16_kernel<<<dim3(8192), blk, 0, stream>>>(
        (const float4*)X, (ushort4*)Xb, B_ * S_ * D_ / 4);
    transpose_cast_kernel<<<dim3(D_ / 32, D_ / 32), tblk, 0, stream>>>(
        Wq, Wqkv, D_, D_);
    transpose_cast_kernel<<<dim3(D_ / 32, D_ / 32), tblk, 0, stream>>>(
        Wk, Wqkv + 1024 * 1024, D_, D_);
    transpose_cast_kernel<<<dim3(D_ / 32, D_ / 32), tblk, 0, stream>>>(
        Wv, Wqkv + 2048 * 1024, D_, D_);
    transpose_cast_kernel<<<dim3(D_ / 32, D_ / 32), tblk, 0, stream>>>(Wo, Wot, D_, D_);
    transpose_cast_kernel<<<dim3(DFF_ / 32, D_ / 32), tblk, 0, stream>>>(W1, W1t, D_, DFF_);
    transpose_cast_kernel<<<dim3(D_ / 32, DFF_ / 32), tblk, 0, stream>>>(W2, W2t, DFF_, D_);

    // fused QKV: [8192,1024]@[3072,1024]^T, 384 blocks x 8 waves
    gemm_qkv<<<dim3(12, 32), blk512, 0, stream>>>(Xb, Wqkv, Qb, Kb, Vb, bq, bk, bv);

    // Vt[b][d][s] = transpose(Vb[b][s][d])
    vtrans_kernel<<<dim3(D_ / 64, S_ / 64, B_), blk, 0, stream>>>(Vb, Vt);

    // scores = Q @ K^T / 32 -> bf16, 256 blocks
    gemm_bt<1, 0, 0><<<dim3(8, 8, 4), blk512, 0, stream>>>(
        Qb, Kb, Sc, nullptr, S_, S_, D_, 0.03125f,
        (long long)S_ * D_, (long long)S_ * D_, (long long)S_ * S_);

    // attn = softmax(scores) + intensity  (bf16)
    softmax_bias_kernel<<<dim3(B_ * S_), blk, 0, stream>>>(Sc, inten, At);

    // AV split-K=2: bf16 partials, 256 blocks
    gemm_bt_sk<2><<<dim3(4, 8, 8), blk512, 0, stream>>>(
        At, Vt, AVp, S_, D_, S_ / 2, S_, S_,
        (long long)S_ * S_, (long long)D_ * S_);
    avred_kernel<<<dim3(8192), blk, 0, stream>>>(
        (const ushort4*)AVp, (const ushort4*)(AVp + MN_d), (ushort4*)AVb,
        (int)(MN_d / 4));

    // O-proj split-K=2: bf16 partials, 256 blocks
    gemm_bt_sk<2><<<dim3(4, 32, 2), blk512, 0, stream>>>(
        AVb, Wot, Op, B_ * S_, D_, D_ / 2, D_, D_, 0, 0);

    // h = LN(Op0 + Op1 + bo + X) -> Hf fp32 + Hb bf16
    ln_red_kernel<1><<<dim3(B_ * S_), blk, 0, stream>>>(
        Op, Op + MN_d, X, bo, g1, be1, Hf, Hb);

    // F1 = leaky_relu(h @ W1 + b1)  (bf16), 512 blocks
    gemm_bt<1, 1, 1><<<dim3(16, 32), blk512, 0, stream>>>(
        Hb, W1t, F1, b1, B_ * S_, DFF_, D_, 1.0f, 0, 0, 0);

    // ffn2 split-K=2: bf16 partials, 256 blocks
    gemm_bt_sk<2><<<dim3(4, 32, 2), blk512, 0, stream>>>(
        F1, W2t, Fp, B_ * S_, D_, DFF_ / 2, DFF_, DFF_, 0, 0);

    // out = LN(Fp0 + Fp1 + b2 + h)
    ln_red_kernel<0><<<dim3(B_ * S_), blk, 0, stream>>>(
        Fp, Fp + MN_d, Hf, b2, g2, be2, out, nullptr);
}

// Round 6
// 550.741 us; speedup vs baseline: 1.0797x; 1.0797x over previous
//
#include <hip/hip_runtime.h>

#define B_   4
#define S_   2048
#define D_   1024
#define DFF_ 4096

typedef __attribute__((ext_vector_type(8))) short short8;
typedef __attribute__((ext_vector_type(4))) float floatx4;

__device__ __forceinline__ unsigned short f2b(float f) {
    unsigned int u = __float_as_uint(f);
    unsigned int r = (u + 0x7fffu + ((u >> 16) & 1u)) >> 16;
    return (unsigned short)r;
}
__device__ __forceinline__ float b2f(unsigned short u) {
    return __uint_as_float((unsigned int)u << 16);
}

// XCD-aware swizzle: blocks sharing an A row-tile (same by) land on one XCD.
__device__ __forceinline__ void swizzle_xy(int gx, int gy, int& bx, int& by) {
    if ((gy & 7) == 0) {
        const int linear = by * gx + bx;
        const int xcd = linear & 7;
        const int slot = linear >> 3;
        const int r = slot / gx;
        by = xcd * (gy >> 3) + r;
        bx = slot - r * gx;
    }
}

#define GLL(src, dst) __builtin_amdgcn_global_load_lds( \
    (const __attribute__((address_space(1))) void*)(src), \
    (__attribute__((address_space(3))) void*)(dst), 16, 0, 0)

__device__ __forceinline__ void barrier_mem() {
    asm volatile("" ::: "memory");
    __builtin_amdgcn_s_barrier();
    asm volatile("" ::: "memory");
}

// ---------------------------------------------------------------------------
// GEMM core: 256x256 tile, BK=64, 512 threads / 8 waves (2M x 4N, 128x64 each).
// [VERIFIED R3 CORE — total 527us, FFN1 72.8us, MfmaUtil 39%, 0 conflicts.]
// 8-phase schedule, ONE barrier per phase: {STG (2x global_load_lds); ds_read
// fragment subset; setprio(1) 16xMFMA setprio(0); [vmcnt(4) at P4/P8];
// s_barrier}. Fragments held across phases: A-half read once per M-half (8
// reads), B-pairs read once per tile (8 reads) => 24 ds_read_b128/K-tile/wave
// — the minimum (R5's uniform-quadrant variant re-read 2x and regressed).
// No explicit lgkmcnt drain: compiler emits per-MFMA lgkm waits -> read tail
// overlaps MFMA issue. vmcnt(4) sits AFTER the MFMA cluster.
// Race derivation (single end-of-phase barrier):
//  - every ds_read is consumed by an MFMA in the same phase => complete
//    before that wave passes the phase barrier;
//  - every STG target region has >=2 barriers since its last reader;
//  - GLL landing gated by {vmcnt(4); barrier} at P4/P8: P4 leaves only
//    t+2:B0,B1 outstanding (t+1 fully landed before P5 reads buf1);
//    P8 leaves only t+3:B0,B1 (t+2 landed before next P1 reads buf0).
// LDS: [256][64] bf16 per operand, double-buffered (128 KiB), 16B-granule
// XOR swizzle slot = g ^ (row&7) via pre-swizzled global source column
// (dest stays linear for global_load_lds); ds_read applies same XOR.
// ---------------------------------------------------------------------------
__device__ __forceinline__ void gemm_core256sq(
    const unsigned short* __restrict__ A,
    const unsigned short* __restrict__ Bt,
    int ldA, int ldB, int K, int m0, int n0,
    unsigned short* __restrict__ lds,   // 65536 shorts: A0|A1|B0|B1 (16384 each)
    floatx4 acc[8][4])
{
    const int tid  = threadIdx.x;   // 0..511
    const int lane = tid & 63;
    const int wave = tid >> 6;      // 0..7
    const int wm   = wave >> 2;     // 0..1 (M half of tile)
    const int wn   = wave & 3;      // 0..3 (N quarter of tile)

    // ---- staging setup: thread covers (row ra, k-granule pg), source col
    //      pre-swizzled so linear LDS dest realizes slot = g ^ (row&7).
    const int ra = tid >> 3;        // 0..63
    const int pg = tid & 7;
    const int cg = (pg ^ (ra & 7)) * 8;
    const unsigned short* gA = A  + (long long)(m0 + ra) * ldA + cg;
    const unsigned short* gB = Bt + (long long)(n0 + ra) * ldB + cg;
    const long long rsA = 64LL * ldA;
    const long long rsB = 64LL * ldB;
    unsigned short* const sAbase = lds + wave * 512;
    unsigned short* const sBbase = lds + 32768 + wave * 512;

    // ---- fragment read setup (16x16x32 bf16): row = base+fr, granule q
    const int fr = lane & 15;
    const int q  = lane >> 4;
    const int sw0 = (q ^ (fr & 7)) * 8;       // k-slice 0 swizzled granule off
    const int sw1 = sw0 ^ 32;                 // k-slice 1 (g = 4+q)
    const unsigned short* const pA = lds + (wm * 128 + fr) * 64;
    const unsigned short* const pB = lds + 32768 + (wn * 64 + fr) * 64;

    short8 Af[4][2];        // [m-frag][k-slice], reloaded per M-half
    short8 Bf[2][2][2];     // [n-pair][n-frag][k-slice], both pairs live

#define STG_A(buf, h, kk) do { \
    const unsigned short* _s = gA + (long long)(h) * 2 * rsA + (kk); \
    unsigned short* _d = sAbase + (buf) * 16384 + (h) * 8192; \
    GLL(_s, _d); GLL(_s + rsA, _d + 4096); } while (0)
#define STG_B(buf, h, kk) do { \
    const unsigned short* _s = gB + (long long)(h) * 2 * rsB + (kk); \
    unsigned short* _d = sBbase + (buf) * 16384 + (h) * 8192; \
    GLL(_s, _d); GLL(_s + rsB, _d + 4096); } while (0)
#define LD_A(bufo, mh) do { \
    _Pragma("unroll") for (int _i = 0; _i < 4; ++_i) { \
        Af[_i][0] = *(const short8*)(pA + (bufo) + (mh) * 4096 + _i * 1024 + sw0); \
        Af[_i][1] = *(const short8*)(pA + (bufo) + (mh) * 4096 + _i * 1024 + sw1); } } while (0)
#define LD_B(bufo, np) do { \
    _Pragma("unroll") for (int _j = 0; _j < 2; ++_j) { \
        Bf[np][_j][0] = *(const short8*)(pB + (bufo) + (np) * 2048 + _j * 1024 + sw0); \
        Bf[np][_j][1] = *(const short8*)(pB + (bufo) + (np) * 2048 + _j * 1024 + sw1); } } while (0)
#define MM(mh, np) do { \
    __builtin_amdgcn_s_setprio(1); \
    _Pragma("unroll") for (int _i = 0; _i < 4; ++_i) \
    _Pragma("unroll") for (int _j = 0; _j < 2; ++_j) \
    _Pragma("unroll") for (int _h = 0; _h < 2; ++_h) \
        acc[(mh) * 4 + _i][(np) * 2 + _j] = __builtin_amdgcn_mfma_f32_16x16x32_bf16( \
            Af[_i][_h], Bf[np][_j][_h], acc[(mh) * 4 + _i][(np) * 2 + _j], 0, 0, 0); \
    __builtin_amdgcn_s_setprio(0); } while (0)
#define VMC(n)  asm volatile("s_waitcnt vmcnt(" #n ")" ::: "memory")

    const int NT = K >> 6;                       // K-tiles; always even, >= 8
    const long long kcap = (long long)K - 64;

    // prologue: tile0 full -> buf0; tile1 B-halves -> buf1 (A comes in P1/P2)
    STG_B(0, 0, 0); STG_B(0, 1, 0);
    STG_A(0, 0, 0); STG_A(0, 1, 0);
    STG_B(1, 0, 64); STG_B(1, 1, 64);
    VMC(4);                 // tile0's 8 GLLs landed; tile1 B may be in flight
    barrier_mem();

    for (int t = 0; t < NT; t += 2) {           // tile t -> buf0, t+1 -> buf1
        const long long k1 = (long long)(t + 1) * 64;   // always valid
        long long k2 = (long long)(t + 2) * 64; if (k2 > kcap) k2 = kcap;
        long long k3 = (long long)(t + 3) * 64; if (k3 > kcap) k3 = kcap;

        // P1: Q0 of t (m0-3 x n0-1); stage t+1:A0 -> buf1 A (freed prev P7)
        STG_A(1, 0, k1);
        LD_A(0, 0); LD_B(0, 0);
        MM(0, 0);
        barrier_mem();
        // P2: Q1 (m0-3 x n2-3); stage t+1:A1 (buf1 A hi freed prev P7)
        STG_A(1, 1, k1);
        LD_B(0, 1);
        MM(0, 1);
        barrier_mem();
        // P3: Q2 (m4-7 x n0-1); stage t+2:B0 -> buf0 B (t's B reads done P2)
        STG_B(0, 0, k2);
        LD_A(0, 1);
        MM(1, 0);
        barrier_mem();
        // P4: Q3 (m4-7 x n2-3); stage t+2:B1; then wait tile t+1 landed
        //     (only t+2:B0,B1 = 4 GLLs may stay in flight), AFTER the MFMAs.
        STG_B(0, 1, k2);
        MM(1, 1);
        VMC(4);
        barrier_mem();
        // P5: Q0 of t+1; stage t+2:A0 -> buf0 A (t's A reads done P3)
        STG_A(0, 0, k2);
        LD_A(16384, 0); LD_B(16384, 0);
        MM(0, 0);
        barrier_mem();
        // P6: Q1; stage t+2:A1
        STG_A(0, 1, k2);
        LD_B(16384, 1);
        MM(0, 1);
        barrier_mem();
        // P7: Q2; stage t+3:B0 -> buf1 B (t+1's B reads done P6)
        STG_B(1, 0, k3);
        LD_A(16384, 1);
        MM(1, 0);
        barrier_mem();
        // P8: Q3; stage t+3:B1; wait tile t+2 landed before next P1.
        STG_B(1, 1, k3);
        MM(1, 1);
        VMC(4);
        barrier_mem();
    }
    VMC(0);   // drain redundant epilogue stages before LDS goes out of scope

#undef STG_A
#undef STG_B
#undef LD_A
#undef LD_B
#undef MM
#undef VMC
}

// ---------------------------------------------------------------------------
__global__ __launch_bounds__(256) void cast_bf16_kernel(
    const float4* __restrict__ src, ushort4* __restrict__ dst, int n4)
{
    int i = blockIdx.x * 256 + threadIdx.x;
    if (i < n4) {
        float4 f = src[i];
        ushort4 u;
        u.x = f2b(f.x); u.y = f2b(f.y); u.z = f2b(f.z); u.w = f2b(f.w);
        dst[i] = u;
    }
}

// ---------------------------------------------------------------------------
// Merged weight transpose+cast: all 6 weight matrices in ONE launch.
// Flattened grid: blocks 0..4095 = four DxD segments (Wq,Wk,Wv,Wo; 1024 each);
// 4096..8191 = W1 [D][DFF] (grid 128x32); 8192..12287 = W2 [DFF][D] (32x128).
// Body identical to the original 32x32-tile transpose_cast kernel.
// ---------------------------------------------------------------------------
__global__ __launch_bounds__(256) void transpose_cast_all_kernel(
    const float* __restrict__ Wq, const float* __restrict__ Wk,
    const float* __restrict__ Wv, const float* __restrict__ Wo,
    const float* __restrict__ W1, const float* __restrict__ W2,
    unsigned short* __restrict__ Wqkv, unsigned short* __restrict__ Wot,
    unsigned short* __restrict__ W1t, unsigned short* __restrict__ W2t)
{
    __shared__ float tile[32][33];
    const int id = blockIdx.x;

    const float* W;
    unsigned short* Wt;
    int Kd, Nd, bx, by;
    if (id < 4096) {
        const int seg = id >> 10;
        const int t = id & 1023;
        bx = t & 31; by = t >> 5;
        Kd = D_; Nd = D_;
        W  = (seg == 0) ? Wq : (seg == 1) ? Wk : (seg == 2) ? Wv : Wo;
        Wt = (seg == 0) ? Wqkv : (seg == 1) ? (Wqkv + 1024 * 1024)
           : (seg == 2) ? (Wqkv + 2048 * 1024) : Wot;
    } else if (id < 8192) {
        const int t = id - 4096;
        bx = t & 127; by = t >> 7;      // grid (DFF/32, D/32)
        Kd = D_; Nd = DFF_;
        W = W1; Wt = W1t;
    } else {
        const int t = id - 8192;
        bx = t & 31; by = t >> 5;       // grid (D/32, DFF/32)
        Kd = DFF_; Nd = D_;
        W = W2; Wt = W2t;
    }
    const int x0 = bx * 32;
    const int y0 = by * 32;
    const int tx = threadIdx.x;
    const int ty = threadIdx.y;
#pragma unroll
    for (int j = 0; j < 32; j += 8)
        tile[ty + j][tx] = W[(long long)(y0 + ty + j) * Nd + x0 + tx];
    __syncthreads();
#pragma unroll
    for (int j = 0; j < 32; j += 8)
        Wt[(long long)(x0 + ty + j) * Kd + y0 + tx] = f2b(tile[tx][ty + j]);
}

// ---------------------------------------------------------------------------
// bf16 transpose: Vb [B][S][D] -> Vt [B][D][S]. 64x64 LDS tiles, ushort4 IO.
// ---------------------------------------------------------------------------
__global__ __launch_bounds__(256) void vtrans_kernel(
    const unsigned short* __restrict__ Vb, unsigned short* __restrict__ Vt)
{
    __shared__ unsigned short tile[64][68];
    const int b  = blockIdx.z;
    const int s0 = blockIdx.y * 64;
    const int d0 = blockIdx.x * 64;
    const int tx = threadIdx.x & 15;
    const int ty = threadIdx.x >> 4;

    const unsigned short* src = Vb + ((long long)b * S_ + s0) * D_ + d0;
#pragma unroll
    for (int j = 0; j < 4; j++) {
        const int s = j * 16 + ty;
        ushort4 v = *(const ushort4*)(src + (long long)s * D_ + tx * 4);
        tile[tx * 4 + 0][s] = v.x;
        tile[tx * 4 + 1][s] = v.y;
        tile[tx * 4 + 2][s] = v.z;
        tile[tx * 4 + 3][s] = v.w;
    }
    __syncthreads();
    unsigned short* dst = Vt + ((long long)b * D_ + d0) * S_ + s0;
#pragma unroll
    for (int j = 0; j < 4; j++) {
        const int d = j * 16 + ty;
        ushort4 v;
        v.x = tile[d][tx * 4 + 0];
        v.y = tile[d][tx * 4 + 1];
        v.z = tile[d][tx * 4 + 2];
        v.w = tile[d][tx * 4 + 3];
        *(ushort4*)(dst + (long long)d * S_ + tx * 4) = v;
    }
}

// ---------------------------------------------------------------------------
// GEMM: C = act(scale * A @ Bt^T + bias), batched via z. 256x256 tile.
// ---------------------------------------------------------------------------
template <int OUT_BF16, int ACT_LEAKY, int HAS_BIAS>
__global__ __launch_bounds__(512, 2) void gemm_bt(
    const unsigned short* __restrict__ A,
    const unsigned short* __restrict__ Bt,
    void* __restrict__ Cptr,
    const float* __restrict__ bias,
    int M, int N, int K, float scale,
    long long sA, long long sB, long long sC)
{
    __shared__ unsigned short lds[65536];

    const int lane = threadIdx.x & 63;
    const int wave = threadIdx.x >> 6;
    const int z    = blockIdx.z;

    int bx = blockIdx.x, by = blockIdx.y;
    swizzle_xy(gridDim.x, gridDim.y, bx, by);
    const int m0 = by * 256;
    const int n0 = bx * 256;

    floatx4 acc[8][4];
#pragma unroll
    for (int i = 0; i < 8; i++)
#pragma unroll
        for (int j = 0; j < 4; j++) acc[i][j] = floatx4{0.f, 0.f, 0.f, 0.f};

    gemm_core256sq(A + (long long)z * sA, Bt + (long long)z * sB,
                   K, K, K, m0, n0, lds, acc);

    const int wr = (wave >> 2) * 128;
    const int wc = (wave & 3) * 64;
    const int cr = (lane >> 4) * 4;
    const int cc = lane & 15;
    float* Cf = (float*)Cptr;
    unsigned short* Cb = (unsigned short*)Cptr;

#pragma unroll
    for (int mi = 0; mi < 8; mi++) {
#pragma unroll
        for (int ni = 0; ni < 4; ni++) {
            const int col = n0 + wc + ni * 16 + cc;
            const float bv = HAS_BIAS ? bias[col] : 0.0f;
#pragma unroll
            for (int r = 0; r < 4; r++) {
                const int row = m0 + wr + mi * 16 + cr + r;
                float v = acc[mi][ni][r] * scale + bv;
                if (ACT_LEAKY) v = (v > 0.0f) ? v : 0.01f * v;
                const long long idx = (long long)z * sC + (long long)row * N + col;
                if (OUT_BF16) Cb[idx] = f2b(v); else Cf[idx] = v;
            }
        }
    }
}

// ---------------------------------------------------------------------------
// Split-K GEMM, 256x256 tile: blockIdx.z = b * NK + ks;
// partial P[(ks*nb + b)][M][N] stored bf16.
// ---------------------------------------------------------------------------
template <int NK>
__global__ __launch_bounds__(512, 2) void gemm_bt_sk(
    const unsigned short* __restrict__ A,
    const unsigned short* __restrict__ Bt,
    unsigned short* __restrict__ P,
    int M, int N, int Kslice, int ldA, int ldB,
    long long sA, long long sB)
{
    __shared__ unsigned short lds[65536];

    const int lane = threadIdx.x & 63;
    const int wave = threadIdx.x >> 6;
    const int z    = blockIdx.z;
    const int ks   = z % NK;
    const int b    = z / NK;
    const int nb   = gridDim.z / NK;

    int bx = blockIdx.x, by = blockIdx.y;
    swizzle_xy(gridDim.x, gridDim.y, bx, by);
    const int m0 = by * 256;
    const int n0 = bx * 256;

    floatx4 acc[8][4];
#pragma unroll
    for (int i = 0; i < 8; i++)
#pragma unroll
        for (int j = 0; j < 4; j++) acc[i][j] = floatx4{0.f, 0.f, 0.f, 0.f};

    gemm_core256sq(A + (long long)b * sA + (long long)ks * Kslice,
                   Bt + (long long)b * sB + (long long)ks * Kslice,
                   ldA, ldB, Kslice, m0, n0, lds, acc);

    const long long pbase = ((long long)ks * nb + b) * (long long)M * N;

    const int wr = (wave >> 2) * 128;
    const int wc = (wave & 3) * 64;
    const int cr = (lane >> 4) * 4;
    const int cc = lane & 15;

#pragma unroll
    for (int mi = 0; mi < 8; mi++) {
#pragma unroll
        for (int ni = 0; ni < 4; ni++) {
            const int col = n0 + wc + ni * 16 + cc;
#pragma unroll
            for (int r = 0; r < 4; r++) {
                const int row = m0 + wr + mi * 16 + cr + r;
                P[pbase + (long long)row * N + col] = f2b(acc[mi][ni][r]);
            }
        }
    }
}

// ---------------------------------------------------------------------------
// Fused QKV GEMM, 256x256 tile: A[8192,1024] @ Wqkvt[3072,1024]^T
// All three segments write coalesced [row][c]; V transposed separately.
// ---------------------------------------------------------------------------
__global__ __launch_bounds__(512, 2) void gemm_qkv(
    const unsigned short* __restrict__ A,
    const unsigned short* __restrict__ Bt,
    unsigned short* __restrict__ Qb,
    unsigned short* __restrict__ Kb,
    unsigned short* __restrict__ Vb,
    const float* __restrict__ bq,
    const float* __restrict__ bk,
    const float* __restrict__ bv)
{
    __shared__ unsigned short lds[65536];

    const int lane = threadIdx.x & 63;
    const int wave = threadIdx.x >> 6;

    int bx = blockIdx.x, by = blockIdx.y;
    swizzle_xy(gridDim.x, gridDim.y, bx, by);
    const int m0 = by * 256;
    const int n0 = bx * 256;

    floatx4 acc[8][4];
#pragma unroll
    for (int i = 0; i < 8; i++)
#pragma unroll
        for (int j = 0; j < 4; j++) acc[i][j] = floatx4{0.f, 0.f, 0.f, 0.f};

    gemm_core256sq(A, Bt, D_, D_, D_, m0, n0, lds, acc);

    const int wr = (wave >> 2) * 128;
    const int wc = (wave & 3) * 64;
    const int cr = (lane >> 4) * 4;
    const int cc = lane & 15;

#pragma unroll
    for (int mi = 0; mi < 8; mi++) {
#pragma unroll
        for (int ni = 0; ni < 4; ni++) {
            const int col = n0 + wc + ni * 16 + cc;
            const int seg = col >> 10;
            const int c = col & 1023;
            const float* bp = (seg == 0) ? bq : ((seg == 1) ? bk : bv);
            unsigned short* dp = (seg == 0) ? Qb : ((seg == 1) ? Kb : Vb);
            const float bval = bp[c];
#pragma unroll
            for (int r = 0; r < 4; r++) {
                const int row = m0 + wr + mi * 16 + cr + r;
                dp[(long long)row * D_ + c] = f2b(acc[mi][ni][r] + bval);
            }
        }
    }
}

// ---------------------------------------------------------------------------
// AV reduce: bf16 out = p0 + p1 (bf16 partials)
// ---------------------------------------------------------------------------
__global__ __launch_bounds__(256) void avred_kernel(
    const ushort4* __restrict__ p0, const ushort4* __restrict__ p1,
    ushort4* __restrict__ dst, int n4)
{
    int i = blockIdx.x * 256 + threadIdx.x;
    if (i < n4) {
        ushort4 a = p0[i], b = p1[i];
        ushort4 u;
        u.x = f2b(b2f(a.x) + b2f(b.x)); u.y = f2b(b2f(a.y) + b2f(b.y));
        u.z = f2b(b2f(a.z) + b2f(b.z)); u.w = f2b(b2f(a.w) + b2f(b.w));
        dst[i] = u;
    }
}

// ---------------------------------------------------------------------------
// Fused split-K reduce + bias + residual + LayerNorm (bf16 partials).
// ---------------------------------------------------------------------------
template <int HAS_OUTB>
__global__ __launch_bounds__(256) void ln_red_kernel(
    const unsigned short* __restrict__ p0, const unsigned short* __restrict__ p1,
    const float* __restrict__ resid, const float* __restrict__ bias,
    const float* __restrict__ g, const float* __restrict__ b,
    float* __restrict__ out_f, unsigned short* __restrict__ out_b)
{
    __shared__ float red[8];
    const long long row = blockIdx.x;
    const int tid = threadIdx.x;
    const ushort4 a0 = ((const ushort4*)(p0 + row * D_))[tid];
    const ushort4 a1 = ((const ushort4*)(p1 + row * D_))[tid];
    const float4 rv = ((const float4*)(resid + row * D_))[tid];
    const float4 bi = ((const float4*)bias)[tid];
    float v0 = b2f(a0.x) + b2f(a1.x) + bi.x + rv.x;
    float v1 = b2f(a0.y) + b2f(a1.y) + bi.y + rv.y;
    float v2 = b2f(a0.z) + b2f(a1.z) + bi.z + rv.z;
    float v3 = b2f(a0.w) + b2f(a1.w) + bi.w + rv.w;

    float s = v0 + v1 + v2 + v3;
#pragma unroll
    for (int o = 32; o > 0; o >>= 1) s += __shfl_xor(s, o);
    if ((tid & 63) == 0) red[tid >> 6] = s;
    __syncthreads();
    const float mean = (red[0] + red[1] + red[2] + red[3]) * (1.0f / D_);

    const float d0 = v0 - mean, d1 = v1 - mean, d2 = v2 - mean, d3 = v3 - mean;
    float qv = d0 * d0 + d1 * d1 + d2 * d2 + d3 * d3;
#pragma unroll
    for (int o = 32; o > 0; o >>= 1) qv += __shfl_xor(qv, o);
    if ((tid & 63) == 0) red[4 + (tid >> 6)] = qv;
    __syncthreads();
    const float var = (red[4] + red[5] + red[6] + red[7]) * (1.0f / D_);
    const float inv = rsqrtf(var + 1e-6f);

    const float4 gv = ((const float4*)g)[tid];
    const float4 bv = ((const float4*)b)[tid];
    const float o0 = d0 * inv * gv.x + bv.x;
    const float o1 = d1 * inv * gv.y + bv.y;
    const float o2 = d2 * inv * gv.z + bv.z;
    const float o3 = d3 * inv * gv.w + bv.w;

    ((float4*)(out_f + row * D_))[tid] = float4{o0, o1, o2, o3};
    if (HAS_OUTB) {
        ushort4 u; u.x = f2b(o0); u.y = f2b(o1); u.z = f2b(o2); u.w = f2b(o3);
        ((ushort4*)(out_b + row * D_))[tid] = u;
    }
}

// ---------------------------------------------------------------------------
// softmax over rows of bf16 scores [B*S, S] + fp32 intensity -> bf16 attn
// ---------------------------------------------------------------------------
__global__ __launch_bounds__(256) void softmax_bias_kernel(
    const unsigned short* __restrict__ scores, const float* __restrict__ intensity,
    unsigned short* __restrict__ attn)
{
    __shared__ float red[8];
    const long long row = blockIdx.x;
    const int tid = threadIdx.x;
    const ushort4* s4 = (const ushort4*)(scores + row * S_);
    const float4* i4 = (const float4*)(intensity + row * S_);
    ushort4* dst = (ushort4*)(attn + row * S_);

    float vv[8];
    {
        ushort4 a = s4[tid], b = s4[tid + 256];
        vv[0] = b2f(a.x); vv[1] = b2f(a.y); vv[2] = b2f(a.z); vv[3] = b2f(a.w);
        vv[4] = b2f(b.x); vv[5] = b2f(b.y); vv[6] = b2f(b.z); vv[7] = b2f(b.w);
    }

    float mx = vv[0];
#pragma unroll
    for (int i = 1; i < 8; i++) mx = fmaxf(mx, vv[i]);
#pragma unroll
    for (int o = 32; o > 0; o >>= 1) mx = fmaxf(mx, __shfl_xor(mx, o));
    if ((tid & 63) == 0) red[tid >> 6] = mx;
    __syncthreads();
    mx = fmaxf(fmaxf(red[0], red[1]), fmaxf(red[2], red[3]));

    float e[8];
    float sum = 0.f;
#pragma unroll
    for (int i = 0; i < 8; i++) { e[i] = __expf(vv[i] - mx); sum += e[i]; }
#pragma unroll
    for (int o = 32; o > 0; o >>= 1) sum += __shfl_xor(sum, o);
    if ((tid & 63) == 0) red[4 + (tid >> 6)] = sum;
    __syncthreads();
    sum = red[4] + red[5] + red[6] + red[7];
    const float rs = 1.0f / sum;

#pragma unroll
    for (int i = 0; i < 2; i++) {
        float4 iv = i4[tid + 256 * i];
        ushort4 o;
        o.x = f2b(e[4 * i + 0] * rs + iv.x);
        o.y = f2b(e[4 * i + 1] * rs + iv.y);
        o.z = f2b(e[4 * i + 2] * rs + iv.z);
        o.w = f2b(e[4 * i + 3] * rs + iv.w);
        dst[tid + 256 * i] = o;
    }
}

// ---------------------------------------------------------------------------
extern "C" void kernel_launch(void* const* d_in, const int* in_sizes, int n_in,
                              void* d_out, int out_size, void* d_ws, size_t ws_size,
                              hipStream_t stream)
{
    const float* X   = (const float*)d_in[0];
    const float* inten = (const float*)d_in[1];
    const float* Wq  = (const float*)d_in[2];
    const float* bq  = (const float*)d_in[3];
    const float* Wk  = (const float*)d_in[4];
    const float* bk  = (const float*)d_in[5];
    const float* Wv  = (const float*)d_in[6];
    const float* bv  = (const float*)d_in[7];
    const float* Wo  = (const float*)d_in[8];
    const float* bo  = (const float*)d_in[9];
    const float* W1  = (const float*)d_in[10];
    const float* b1  = (const float*)d_in[11];
    const float* W2  = (const float*)d_in[12];
    const float* b2  = (const float*)d_in[13];
    const float* g1  = (const float*)d_in[14];
    const float* be1 = (const float*)d_in[15];
    const float* g2  = (const float*)d_in[16];
    const float* be2 = (const float*)d_in[17];
    float* out = (float*)d_out;

    char* ws = (char*)d_ws;
    const size_t MB = 1ull << 20;
    // timeline-aliased layout, peak 184 MB:
    unsigned short* Xb   = (unsigned short*)(ws + 0);        // 16MB; dead after QKV
    unsigned short* Wqkv = (unsigned short*)(ws + 16 * MB);  // 6MB
    unsigned short* Wot  = (unsigned short*)(ws + 22 * MB);  // 2MB
    unsigned short* W1t  = (unsigned short*)(ws + 24 * MB);  // 8MB
    unsigned short* W2t  = (unsigned short*)(ws + 32 * MB);  // 8MB
    unsigned short* Qb   = (unsigned short*)(ws + 40 * MB);  // 16MB; dead after scores
    unsigned short* Kb   = (unsigned short*)(ws + 56 * MB);  // 16MB; dead after scores
    unsigned short* Vt   = (unsigned short*)(ws + 72 * MB);  // 16MB; dead after attnV
    unsigned short* Sc   = (unsigned short*)(ws + 88 * MB);  // 32MB bf16; dead after softmax
    unsigned short* Vb   = (unsigned short*)(ws + 152 * MB); // 16MB; dead after vtrans
    unsigned short* At   = (unsigned short*)(ws + 152 * MB); // 32MB (after Vb dead); dead after AV
    unsigned short* AVp  = (unsigned short*)(ws + 88 * MB);  // 2x16MB bf16 (reuse Sc)
    unsigned short* AVb  = (unsigned short*)(ws + 0);        // 16MB (reuse Xb)
    unsigned short* Op   = (unsigned short*)(ws + 152 * MB); // 2x16MB bf16 (reuse At)
    float*          Hf   = (float*)(ws + 40 * MB);           // 32MB (reuse Qb+Kb)
    unsigned short* Hb   = (unsigned short*)(ws + 72 * MB);  // 16MB (reuse Vt)
    unsigned short* F1   = (unsigned short*)(ws + 88 * MB);  // 64MB (reuse AVp + free)
    unsigned short* Fp   = (unsigned short*)(ws + 152 * MB); // 2x16MB bf16 (reuse Op)

    const dim3 blk(256);
    const dim3 blk512(512);
    const dim3 tblk(32, 8);
    const long long MN_d = (long long)B_ * S_ * D_;

    // input cast + ALL weight transposes (one launch)
    cast_bf16_kernel<<<dim3(8192), blk, 0, stream>>>(
        (const float4*)X, (ushort4*)Xb, B_ * S_ * D_ / 4);
    transpose_cast_all_kernel<<<dim3(12288), tblk, 0, stream>>>(
        Wq, Wk, Wv, Wo, W1, W2, Wqkv, Wot, W1t, W2t);

    // fused QKV: [8192,1024]@[3072,1024]^T, 384 blocks x 8 waves
    gemm_qkv<<<dim3(12, 32), blk512, 0, stream>>>(Xb, Wqkv, Qb, Kb, Vb, bq, bk, bv);

    // Vt[b][d][s] = transpose(Vb[b][s][d])
    vtrans_kernel<<<dim3(D_ / 64, S_ / 64, B_), blk, 0, stream>>>(Vb, Vt);

    // scores = Q @ K^T / 32 -> bf16, 256 blocks
    gemm_bt<1, 0, 0><<<dim3(8, 8, 4), blk512, 0, stream>>>(
        Qb, Kb, Sc, nullptr, S_, S_, D_, 0.03125f,
        (long long)S_ * D_, (long long)S_ * D_, (long long)S_ * S_);

    // attn = softmax(scores) + intensity  (bf16)
    softmax_bias_kernel<<<dim3(B_ * S_), blk, 0, stream>>>(Sc, inten, At);

    // AV split-K=2: bf16 partials, 256 blocks
    gemm_bt_sk<2><<<dim3(4, 8, 8), blk512, 0, stream>>>(
        At, Vt, AVp, S_, D_, S_ / 2, S_, S_,
        (long long)S_ * S_, (long long)D_ * S_);
    avred_kernel<<<dim3(8192), blk, 0, stream>>>(
        (const ushort4*)AVp, (const ushort4*)(AVp + MN_d), (ushort4*)AVb,
        (int)(MN_d / 4));

    // O-proj split-K=2: bf16 partials, 256 blocks
    gemm_bt_sk<2><<<dim3(4, 32, 2), blk512, 0, stream>>>(
        AVb, Wot, Op, B_ * S_, D_, D_ / 2, D_, D_, 0, 0);

    // h = LN(Op0 + Op1 + bo + X) -> Hf fp32 + Hb bf16
    ln_red_kernel<1><<<dim3(B_ * S_), blk, 0, stream>>>(
        Op, Op + MN_d, X, bo, g1, be1, Hf, Hb);

    // F1 = leaky_relu(h @ W1 + b1)  (bf16), 512 blocks
    gemm_bt<1, 1, 1><<<dim3(16, 32), blk512, 0, stream>>>(
        Hb, W1t, F1, b1, B_ * S_, DFF_, D_, 1.0f, 0, 0, 0);

    // ffn2 split-K=2: bf16 partials, 256 blocks
    gemm_bt_sk<2><<<dim3(4, 32, 2), blk512, 0, stream>>>(
        F1, W2t, Fp, B_ * S_, D_, DFF_ / 2, DFF_, DFF_, 0, 0);

    // out = LN(Fp0 + Fp1 + b2 + h)
    ln_red_kernel<0><<<dim3(B_ * S_), blk, 0, stream>>>(
        Fp, Fp + MN_d, Hf, b2, g2, be2, out, nullptr);
}

// Round 9
// 519.262 us; speedup vs baseline: 1.1451x; 1.0606x over previous
//
#include <hip/hip_runtime.h>

#define B_   4
#define S_   2048
#define D_   1024
#define DFF_ 4096

typedef __attribute__((ext_vector_type(8))) short short8;
typedef __attribute__((ext_vector_type(4))) float floatx4;

__device__ __forceinline__ unsigned short f2b(float f) {
    unsigned int u = __float_as_uint(f);
    unsigned int r = (u + 0x7fffu + ((u >> 16) & 1u)) >> 16;
    return (unsigned short)r;
}
__device__ __forceinline__ float b2f(unsigned short u) {
    return __uint_as_float((unsigned int)u << 16);
}

// XCD-aware swizzle: blocks sharing an A row-tile (same by) land on one XCD.
__device__ __forceinline__ void swizzle_xy(int gx, int gy, int& bx, int& by) {
    if ((gy & 7) == 0) {
        const int linear = by * gx + bx;
        const int xcd = linear & 7;
        const int slot = linear >> 3;
        const int r = slot / gx;
        by = xcd * (gy >> 3) + r;
        bx = slot - r * gx;
    }
}

#define GLL(src, dst) __builtin_amdgcn_global_load_lds( \
    (const __attribute__((address_space(1))) void*)(src), \
    (__attribute__((address_space(3))) void*)(dst), 16, 0, 0)

// m201-EXACT sync idiom (hardware-verified at 1563 TF on this chip):
// bare s_barrier (unmodeled side effects -> MI scheduler chains all memory
// ops to it; does NOT force a waitcnt drain), bare volatile no-clobber
// waitcnt asm (assembler-checked, no mayLoad/mayStore -> no forced drain).
// NO "memory" clobbers (they drain vmcnt -> R0-R6 ~940 TF ceiling) and
// NO sched_barrier wrappers (the one untested element in R7/R8's variants).
#define WAIT_VM4() asm volatile("s_waitcnt vmcnt(4)")
#define WAIT_VM0() asm volatile("s_waitcnt vmcnt(0)")
#define BARRIER()  __builtin_amdgcn_s_barrier()

// ---------------------------------------------------------------------------
// GEMM core: 256x256 tile, BK=64, 512 threads / 8 waves (2M x 4N, 128x64 each).
// R3-verified 8-phase schedule (527us total with fenced sync) + m201-exact
// clobber-free sync so the counted vmcnt(4) pipeline survives to ISA.
// Per phase: {STG (2x global_load_lds); ds_read fragment subset; setprio(1)
// 16xMFMA setprio(0); [vmcnt(4) at P4/P8]; s_barrier}. Fragments held across
// phases: 24 ds_read_b128/K-tile/wave (minimum). ds_reads are compiler-visible
// loads -> hipcc inserts fine-grained lgkm waits before dependent MFMAs
// (no manual lgkm needed; rule-18 applies only to inline-asm ds_reads).
// Race derivation (single end-of-phase barrier):
//  - every ds_read is consumed by an MFMA in the same phase => drained by
//    compiler lgkm waits before that wave passes the phase barrier;
//  - every STG target region has >=2 barriers since its last reader;
//  - GLL landing gated by {vmcnt(4); barrier} at P4/P8: P4 leaves only
//    t+2:B0,B1 outstanding (t+1 fully landed before P5 reads buf1);
//    P8 leaves only t+3:B0,B1 (t+2 landed before next P1 reads buf0);
//  - bare s_barrier orders memory ops at MI level (unmodeled side effects).
// LDS: [256][64] bf16 per operand, double-buffered (128 KiB), 16B-granule
// XOR swizzle slot = g ^ (row&7) via pre-swizzled global source column
// (dest stays linear for global_load_lds); ds_read applies same XOR.
// Epilogue WAIT_VM0: redundant clamped stages must land before the workgroup
// exits (stale GLLs hitting a reallocated LDS would corrupt the next block).
// ---------------------------------------------------------------------------
__device__ __forceinline__ void gemm_core256sq(
    const unsigned short* __restrict__ A,
    const unsigned short* __restrict__ Bt,
    int ldA, int ldB, int K, int m0, int n0,
    unsigned short* __restrict__ lds,   // 65536 shorts: A0|A1|B0|B1 (16384 each)
    floatx4 acc[8][4])
{
    const int tid  = threadIdx.x;   // 0..511
    const int lane = tid & 63;
    const int wave = tid >> 6;      // 0..7
    const int wm   = wave >> 2;     // 0..1 (M half of tile)
    const int wn   = wave & 3;      // 0..3 (N quarter of tile)

    // ---- staging setup: thread covers (row ra, k-granule pg), source col
    //      pre-swizzled so linear LDS dest realizes slot = g ^ (row&7).
    const int ra = tid >> 3;        // 0..63
    const int pg = tid & 7;
    const int cg = (pg ^ (ra & 7)) * 8;
    const unsigned short* gA = A  + (long long)(m0 + ra) * ldA + cg;
    const unsigned short* gB = Bt + (long long)(n0 + ra) * ldB + cg;
    const long long rsA = 64LL * ldA;
    const long long rsB = 64LL * ldB;
    unsigned short* const sAbase = lds + wave * 512;
    unsigned short* const sBbase = lds + 32768 + wave * 512;

    // ---- fragment read setup (16x16x32 bf16): row = base+fr, granule q
    const int fr = lane & 15;
    const int q  = lane >> 4;
    const int sw0 = (q ^ (fr & 7)) * 8;       // k-slice 0 swizzled granule off
    const int sw1 = sw0 ^ 32;                 // k-slice 1 (g = 4+q)
    const unsigned short* const pA = lds + (wm * 128 + fr) * 64;
    const unsigned short* const pB = lds + 32768 + (wn * 64 + fr) * 64;

    short8 Af[4][2];        // [m-frag][k-slice], reloaded per M-half
    short8 Bf[2][2][2];     // [n-pair][n-frag][k-slice], both pairs live

#define STG_A(buf, h, kk) do { \
    const unsigned short* _s = gA + (long long)(h) * 2 * rsA + (kk); \
    unsigned short* _d = sAbase + (buf) * 16384 + (h) * 8192; \
    GLL(_s, _d); GLL(_s + rsA, _d + 4096); } while (0)
#define STG_B(buf, h, kk) do { \
    const unsigned short* _s = gB + (long long)(h) * 2 * rsB + (kk); \
    unsigned short* _d = sBbase + (buf) * 16384 + (h) * 8192; \
    GLL(_s, _d); GLL(_s + rsB, _d + 4096); } while (0)
#define LD_A(bufo, mh) do { \
    _Pragma("unroll") for (int _i = 0; _i < 4; ++_i) { \
        Af[_i][0] = *(const short8*)(pA + (bufo) + (mh) * 4096 + _i * 1024 + sw0); \
        Af[_i][1] = *(const short8*)(pA + (bufo) + (mh) * 4096 + _i * 1024 + sw1); } } while (0)
#define LD_B(bufo, np) do { \
    _Pragma("unroll") for (int _j = 0; _j < 2; ++_j) { \
        Bf[np][_j][0] = *(const short8*)(pB + (bufo) + (np) * 2048 + _j * 1024 + sw0); \
        Bf[np][_j][1] = *(const short8*)(pB + (bufo) + (np) * 2048 + _j * 1024 + sw1); } } while (0)
#define MM(mh, np) do { \
    __builtin_amdgcn_s_setprio(1); \
    _Pragma("unroll") for (int _i = 0; _i < 4; ++_i) \
    _Pragma("unroll") for (int _j = 0; _j < 2; ++_j) \
    _Pragma("unroll") for (int _h = 0; _h < 2; ++_h) \
        acc[(mh) * 4 + _i][(np) * 2 + _j] = __builtin_amdgcn_mfma_f32_16x16x32_bf16( \
            Af[_i][_h], Bf[np][_j][_h], acc[(mh) * 4 + _i][(np) * 2 + _j], 0, 0, 0); \
    __builtin_amdgcn_s_setprio(0); } while (0)

    const int NT = K >> 6;                       // K-tiles; always even, >= 8
    const long long kcap = (long long)K - 64;

    // prologue: tile0 full -> buf0; tile1 B-halves -> buf1 (A comes in P1/P2)
    STG_B(0, 0, 0); STG_B(0, 1, 0);
    STG_A(0, 0, 0); STG_A(0, 1, 0);
    STG_B(1, 0, 64); STG_B(1, 1, 64);
    WAIT_VM4();             // tile0's 8 GLLs landed; tile1 B may be in flight
    BARRIER();

    for (int t = 0; t < NT; t += 2) {           // tile t -> buf0, t+1 -> buf1
        const long long k1 = (long long)(t + 1) * 64;   // always valid
        long long k2 = (long long)(t + 2) * 64; if (k2 > kcap) k2 = kcap;
        long long k3 = (long long)(t + 3) * 64; if (k3 > kcap) k3 = kcap;

        // P1: Q0 of t (m0-3 x n0-1); stage t+1:A0 -> buf1 A (freed prev P7)
        STG_A(1, 0, k1);
        LD_A(0, 0); LD_B(0, 0);
        MM(0, 0);
        BARRIER();
        // P2: Q1 (m0-3 x n2-3); stage t+1:A1 (buf1 A hi freed prev P7)
        STG_A(1, 1, k1);
        LD_B(0, 1);
        MM(0, 1);
        BARRIER();
        // P3: Q2 (m4-7 x n0-1); stage t+2:B0 -> buf0 B (t's B reads done P2)
        STG_B(0, 0, k2);
        LD_A(0, 1);
        MM(1, 0);
        BARRIER();
        // P4: Q3 (m4-7 x n2-3); stage t+2:B1; then wait tile t+1 landed
        //     (only t+2:B0,B1 = 4 GLLs may stay in flight), AFTER the MFMAs.
        STG_B(0, 1, k2);
        MM(1, 1);
        WAIT_VM4();
        BARRIER();
        // P5: Q0 of t+1; stage t+2:A0 -> buf0 A (t's A reads done P3)
        STG_A(0, 0, k2);
        LD_A(16384, 0); LD_B(16384, 0);
        MM(0, 0);
        BARRIER();
        // P6: Q1; stage t+2:A1
        STG_A(0, 1, k2);
        LD_B(16384, 1);
        MM(0, 1);
        BARRIER();
        // P7: Q2; stage t+3:B0 -> buf1 B (t+1's B reads done P6)
        STG_B(1, 0, k3);
        LD_A(16384, 1);
        MM(1, 0);
        BARRIER();
        // P8: Q3; stage t+3:B1; wait tile t+2 landed before next P1.
        STG_B(1, 1, k3);
        MM(1, 1);
        WAIT_VM4();
        BARRIER();
    }
    WAIT_VM0();   // drain redundant epilogue stages before LDS is deallocated

#undef STG_A
#undef STG_B
#undef LD_A
#undef LD_B
#undef MM
}

// ---------------------------------------------------------------------------
__global__ __launch_bounds__(256) void cast_bf16_kernel(
    const float4* __restrict__ src, ushort4* __restrict__ dst, int n4)
{
    int i = blockIdx.x * 256 + threadIdx.x;
    if (i < n4) {
        float4 f = src[i];
        ushort4 u;
        u.x = f2b(f.x); u.y = f2b(f.y); u.z = f2b(f.z); u.w = f2b(f.w);
        dst[i] = u;
    }
}

// ---------------------------------------------------------------------------
// Merged weight transpose+cast: all 6 weight matrices in ONE launch.
// Flattened grid: blocks 0..4095 = four DxD segments (Wq,Wk,Wv,Wo; 1024 each);
// 4096..8191 = W1 [D][DFF] (grid 128x32); 8192..12287 = W2 [DFF][D] (32x128).
// ---------------------------------------------------------------------------
__global__ __launch_bounds__(256) void transpose_cast_all_kernel(
    const float* __restrict__ Wq, const float* __restrict__ Wk,
    const float* __restrict__ Wv, const float* __restrict__ Wo,
    const float* __restrict__ W1, const float* __restrict__ W2,
    unsigned short* __restrict__ Wqkv, unsigned short* __restrict__ Wot,
    unsigned short* __restrict__ W1t, unsigned short* __restrict__ W2t)
{
    __shared__ float tile[32][33];
    const int id = blockIdx.x;

    const float* W;
    unsigned short* Wt;
    int Kd, Nd, bx, by;
    if (id < 4096) {
        const int seg = id >> 10;
        const int t = id & 1023;
        bx = t & 31; by = t >> 5;
        Kd = D_; Nd = D_;
        W  = (seg == 0) ? Wq : (seg == 1) ? Wk : (seg == 2) ? Wv : Wo;
        Wt = (seg == 0) ? Wqkv : (seg == 1) ? (Wqkv + 1024 * 1024)
           : (seg == 2) ? (Wqkv + 2048 * 1024) : Wot;
    } else if (id < 8192) {
        const int t = id - 4096;
        bx = t & 127; by = t >> 7;      // grid (DFF/32, D/32)
        Kd = D_; Nd = DFF_;
        W = W1; Wt = W1t;
    } else {
        const int t = id - 8192;
        bx = t & 31; by = t >> 5;       // grid (D/32, DFF/32)
        Kd = DFF_; Nd = D_;
        W = W2; Wt = W2t;
    }
    const int x0 = bx * 32;
    const int y0 = by * 32;
    const int tx = threadIdx.x;
    const int ty = threadIdx.y;
#pragma unroll
    for (int j = 0; j < 32; j += 8)
        tile[ty + j][tx] = W[(long long)(y0 + ty + j) * Nd + x0 + tx];
    __syncthreads();
#pragma unroll
    for (int j = 0; j < 32; j += 8)
        Wt[(long long)(x0 + ty + j) * Kd + y0 + tx] = f2b(tile[tx][ty + j]);
}

// ---------------------------------------------------------------------------
// bf16 transpose: Vb [B][S][D] -> Vt [B][D][S]. 64x64 LDS tiles, ushort4 IO.
// ---------------------------------------------------------------------------
__global__ __launch_bounds__(256) void vtrans_kernel(
    const unsigned short* __restrict__ Vb, unsigned short* __restrict__ Vt)
{
    __shared__ unsigned short tile[64][68];
    const int b  = blockIdx.z;
    const int s0 = blockIdx.y * 64;
    const int d0 = blockIdx.x * 64;
    const int tx = threadIdx.x & 15;
    const int ty = threadIdx.x >> 4;

    const unsigned short* src = Vb + ((long long)b * S_ + s0) * D_ + d0;
#pragma unroll
    for (int j = 0; j < 4; j++) {
        const int s = j * 16 + ty;
        ushort4 v = *(const ushort4*)(src + (long long)s * D_ + tx * 4);
        tile[tx * 4 + 0][s] = v.x;
        tile[tx * 4 + 1][s] = v.y;
        tile[tx * 4 + 2][s] = v.z;
        tile[tx * 4 + 3][s] = v.w;
    }
    __syncthreads();
    unsigned short* dst = Vt + ((long long)b * D_ + d0) * S_ + s0;
#pragma unroll
    for (int j = 0; j < 4; j++) {
        const int d = j * 16 + ty;
        ushort4 v;
        v.x = tile[d][tx * 4 + 0];
        v.y = tile[d][tx * 4 + 1];
        v.z = tile[d][tx * 4 + 2];
        v.w = tile[d][tx * 4 + 3];
        *(ushort4*)(dst + (long long)d * S_ + tx * 4) = v;
    }
}

// ---------------------------------------------------------------------------
// GEMM: C = act(scale * A @ Bt^T + bias), batched via z. 256x256 tile.
// ---------------------------------------------------------------------------
template <int OUT_BF16, int ACT_LEAKY, int HAS_BIAS>
__global__ __launch_bounds__(512, 2) void gemm_bt(
    const unsigned short* __restrict__ A,
    const unsigned short* __restrict__ Bt,
    void* __restrict__ Cptr,
    const float* __restrict__ bias,
    int M, int N, int K, float scale,
    long long sA, long long sB, long long sC)
{
    __shared__ unsigned short lds[65536];

    const int lane = threadIdx.x & 63;
    const int wave = threadIdx.x >> 6;
    const int z    = blockIdx.z;

    int bx = blockIdx.x, by = blockIdx.y;
    swizzle_xy(gridDim.x, gridDim.y, bx, by);
    const int m0 = by * 256;
    const int n0 = bx * 256;

    floatx4 acc[8][4];
#pragma unroll
    for (int i = 0; i < 8; i++)
#pragma unroll
        for (int j = 0; j < 4; j++) acc[i][j] = floatx4{0.f, 0.f, 0.f, 0.f};

    gemm_core256sq(A + (long long)z * sA, Bt + (long long)z * sB,
                   K, K, K, m0, n0, lds, acc);

    const int wr = (wave >> 2) * 128;
    const int wc = (wave & 3) * 64;
    const int cr = (lane >> 4) * 4;
    const int cc = lane & 15;
    float* Cf = (float*)Cptr;
    unsigned short* Cb = (unsigned short*)Cptr;

#pragma unroll
    for (int mi = 0; mi < 8; mi++) {
#pragma unroll
        for (int ni = 0; ni < 4; ni++) {
            const int col = n0 + wc + ni * 16 + cc;
            const float bv = HAS_BIAS ? bias[col] : 0.0f;
#pragma unroll
            for (int r = 0; r < 4; r++) {
                const int row = m0 + wr + mi * 16 + cr + r;
                float v = acc[mi][ni][r] * scale + bv;
                if (ACT_LEAKY) v = (v > 0.0f) ? v : 0.01f * v;
                const long long idx = (long long)z * sC + (long long)row * N + col;
                if (OUT_BF16) Cb[idx] = f2b(v); else Cf[idx] = v;
            }
        }
    }
}

// ---------------------------------------------------------------------------
// Split-K GEMM, 256x256 tile: blockIdx.z = b * NK + ks;
// partial P[(ks*nb + b)][M][N] stored bf16.
// ---------------------------------------------------------------------------
template <int NK>
__global__ __launch_bounds__(512, 2) void gemm_bt_sk(
    const unsigned short* __restrict__ A,
    const unsigned short* __restrict__ Bt,
    unsigned short* __restrict__ P,
    int M, int N, int Kslice, int ldA, int ldB,
    long long sA, long long sB)
{
    __shared__ unsigned short lds[65536];

    const int lane = threadIdx.x & 63;
    const int wave = threadIdx.x >> 6;
    const int z    = blockIdx.z;
    const int ks   = z % NK;
    const int b    = z / NK;
    const int nb   = gridDim.z / NK;

    int bx = blockIdx.x, by = blockIdx.y;
    swizzle_xy(gridDim.x, gridDim.y, bx, by);
    const int m0 = by * 256;
    const int n0 = bx * 256;

    floatx4 acc[8][4];
#pragma unroll
    for (int i = 0; i < 8; i++)
#pragma unroll
        for (int j = 0; j < 4; j++) acc[i][j] = floatx4{0.f, 0.f, 0.f, 0.f};

    gemm_core256sq(A + (long long)b * sA + (long long)ks * Kslice,
                   Bt + (long long)b * sB + (long long)ks * Kslice,
                   ldA, ldB, Kslice, m0, n0, lds, acc);

    const long long pbase = ((long long)ks * nb + b) * (long long)M * N;

    const int wr = (wave >> 2) * 128;
    const int wc = (wave & 3) * 64;
    const int cr = (lane >> 4) * 4;
    const int cc = lane & 15;

#pragma unroll
    for (int mi = 0; mi < 8; mi++) {
#pragma unroll
        for (int ni = 0; ni < 4; ni++) {
            const int col = n0 + wc + ni * 16 + cc;
#pragma unroll
            for (int r = 0; r < 4; r++) {
                const int row = m0 + wr + mi * 16 + cr + r;
                P[pbase + (long long)row * N + col] = f2b(acc[mi][ni][r]);
            }
        }
    }
}

// ---------------------------------------------------------------------------
// Fused QKV GEMM, 256x256 tile: A[8192,1024] @ Wqkvt[3072,1024]^T
// All three segments write coalesced [row][c]; V transposed separately.
// ---------------------------------------------------------------------------
__global__ __launch_bounds__(512, 2) void gemm_qkv(
    const unsigned short* __restrict__ A,
    const unsigned short* __restrict__ Bt,
    unsigned short* __restrict__ Qb,
    unsigned short* __restrict__ Kb,
    unsigned short* __restrict__ Vb,
    const float* __restrict__ bq,
    const float* __restrict__ bk,
    const float* __restrict__ bv)
{
    __shared__ unsigned short lds[65536];

    const int lane = threadIdx.x & 63;
    const int wave = threadIdx.x >> 6;

    int bx = blockIdx.x, by = blockIdx.y;
    swizzle_xy(gridDim.x, gridDim.y, bx, by);
    const int m0 = by * 256;
    const int n0 = bx * 256;

    floatx4 acc[8][4];
#pragma unroll
    for (int i = 0; i < 8; i++)
#pragma unroll
        for (int j = 0; j < 4; j++) acc[i][j] = floatx4{0.f, 0.f, 0.f, 0.f};

    gemm_core256sq(A, Bt, D_, D_, D_, m0, n0, lds, acc);

    const int wr = (wave >> 2) * 128;
    const int wc = (wave & 3) * 64;
    const int cr = (lane >> 4) * 4;
    const int cc = lane & 15;

#pragma unroll
    for (int mi = 0; mi < 8; mi++) {
#pragma unroll
        for (int ni = 0; ni < 4; ni++) {
            const int col = n0 + wc + ni * 16 + cc;
            const int seg = col >> 10;
            const int c = col & 1023;
            const float* bp = (seg == 0) ? bq : ((seg == 1) ? bk : bv);
            unsigned short* dp = (seg == 0) ? Qb : ((seg == 1) ? Kb : Vb);
            const float bval = bp[c];
#pragma unroll
            for (int r = 0; r < 4; r++) {
                const int row = m0 + wr + mi * 16 + cr + r;
                dp[(long long)row * D_ + c] = f2b(acc[mi][ni][r] + bval);
            }
        }
    }
}

// ---------------------------------------------------------------------------
// AV reduce: bf16 out = p0 + p1 (bf16 partials)
// ---------------------------------------------------------------------------
__global__ __launch_bounds__(256) void avred_kernel(
    const ushort4* __restrict__ p0, const ushort4* __restrict__ p1,
    ushort4* __restrict__ dst, int n4)
{
    int i = blockIdx.x * 256 + threadIdx.x;
    if (i < n4) {
        ushort4 a = p0[i], b = p1[i];
        ushort4 u;
        u.x = f2b(b2f(a.x) + b2f(b.x)); u.y = f2b(b2f(a.y) + b2f(b.y));
        u.z = f2b(b2f(a.z) + b2f(b.z)); u.w = f2b(b2f(a.w) + b2f(b.w));
        dst[i] = u;
    }
}

// ---------------------------------------------------------------------------
// Fused split-K reduce + bias + residual + LayerNorm (bf16 partials).
// ---------------------------------------------------------------------------
template <int HAS_OUTB>
__global__ __launch_bounds__(256) void ln_red_kernel(
    const unsigned short* __restrict__ p0, const unsigned short* __restrict__ p1,
    const float* __restrict__ resid, const float* __restrict__ bias,
    const float* __restrict__ g, const float* __restrict__ b,
    float* __restrict__ out_f, unsigned short* __restrict__ out_b)
{
    __shared__ float red[8];
    const long long row = blockIdx.x;
    const int tid = threadIdx.x;
    const ushort4 a0 = ((const ushort4*)(p0 + row * D_))[tid];
    const ushort4 a1 = ((const ushort4*)(p1 + row * D_))[tid];
    const float4 rv = ((const float4*)(resid + row * D_))[tid];
    const float4 bi = ((const float4*)bias)[tid];
    float v0 = b2f(a0.x) + b2f(a1.x) + bi.x + rv.x;
    float v1 = b2f(a0.y) + b2f(a1.y) + bi.y + rv.y;
    float v2 = b2f(a0.z) + b2f(a1.z) + bi.z + rv.z;
    float v3 = b2f(a0.w) + b2f(a1.w) + bi.w + rv.w;

    float s = v0 + v1 + v2 + v3;
#pragma unroll
    for (int o = 32; o > 0; o >>= 1) s += __shfl_xor(s, o);
    if ((tid & 63) == 0) red[tid >> 6] = s;
    __syncthreads();
    const float mean = (red[0] + red[1] + red[2] + red[3]) * (1.0f / D_);

    const float d0 = v0 - mean, d1 = v1 - mean, d2 = v2 - mean, d3 = v3 - mean;
    float qv = d0 * d0 + d1 * d1 + d2 * d2 + d3 * d3;
#pragma unroll
    for (int o = 32; o > 0; o >>= 1) qv += __shfl_xor(qv, o);
    if ((tid & 63) == 0) red[4 + (tid >> 6)] = qv;
    __syncthreads();
    const float var = (red[4] + red[5] + red[6] + red[7]) * (1.0f / D_);
    const float inv = rsqrtf(var + 1e-6f);

    const float4 gv = ((const float4*)g)[tid];
    const float4 bv = ((const float4*)b)[tid];
    const float o0 = d0 * inv * gv.x + bv.x;
    const float o1 = d1 * inv * gv.y + bv.y;
    const float o2 = d2 * inv * gv.z + bv.z;
    const float o3 = d3 * inv * gv.w + bv.w;

    ((float4*)(out_f + row * D_))[tid] = float4{o0, o1, o2, o3};
    if (HAS_OUTB) {
        ushort4 u; u.x = f2b(o0); u.y = f2b(o1); u.z = f2b(o2); u.w = f2b(o3);
        ((ushort4*)(out_b + row * D_))[tid] = u;
    }
}

// ---------------------------------------------------------------------------
// softmax over rows of bf16 scores [B*S, S] + fp32 intensity -> bf16 attn
// ---------------------------------------------------------------------------
__global__ __launch_bounds__(256) void softmax_bias_kernel(
    const unsigned short* __restrict__ scores, const float* __restrict__ intensity,
    unsigned short* __restrict__ attn)
{
    __shared__ float red[8];
    const long long row = blockIdx.x;
    const int tid = threadIdx.x;
    const ushort4* s4 = (const ushort4*)(scores + row * S_);
    const float4* i4 = (const float4*)(intensity + row * S_);
    ushort4* dst = (ushort4*)(attn + row * S_);

    float vv[8];
    {
        ushort4 a = s4[tid], b = s4[tid + 256];
        vv[0] = b2f(a.x); vv[1] = b2f(a.y); vv[2] = b2f(a.z); vv[3] = b2f(a.w);
        vv[4] = b2f(b.x); vv[5] = b2f(b.y); vv[6] = b2f(b.z); vv[7] = b2f(b.w);
    }

    float mx = vv[0];
#pragma unroll
    for (int i = 1; i < 8; i++) mx = fmaxf(mx, vv[i]);
#pragma unroll
    for (int o = 32; o > 0; o >>= 1) mx = fmaxf(mx, __shfl_xor(mx, o));
    if ((tid & 63) == 0) red[tid >> 6] = mx;
    __syncthreads();
    mx = fmaxf(fmaxf(red[0], red[1]), fmaxf(red[2], red[3]));

    float e[8];
    float sum = 0.f;
#pragma unroll
    for (int i = 0; i < 8; i++) { e[i] = __expf(vv[i] - mx); sum += e[i]; }
#pragma unroll
    for (int o = 32; o > 0; o >>= 1) sum += __shfl_xor(sum, o);
    if ((tid & 63) == 0) red[4 + (tid >> 6)] = sum;
    __syncthreads();
    sum = red[4] + red[5] + red[6] + red[7];
    const float rs = 1.0f / sum;

#pragma unroll
    for (int i = 0; i < 2; i++) {
        float4 iv = i4[tid + 256 * i];
        ushort4 o;
        o.x = f2b(e[4 * i + 0] * rs + iv.x);
        o.y = f2b(e[4 * i + 1] * rs + iv.y);
        o.z = f2b(e[4 * i + 2] * rs + iv.z);
        o.w = f2b(e[4 * i + 3] * rs + iv.w);
        dst[tid + 256 * i] = o;
    }
}

// ---------------------------------------------------------------------------
extern "C" void kernel_launch(void* const* d_in, const int* in_sizes, int n_in,
                              void* d_out, int out_size, void* d_ws, size_t ws_size,
                              hipStream_t stream)
{
    const float* X   = (const float*)d_in[0];
    const float* inten = (const float*)d_in[1];
    const float* Wq  = (const float*)d_in[2];
    const float* bq  = (const float*)d_in[3];
    const float* Wk  = (const float*)d_in[4];
    const float* bk  = (const float*)d_in[5];
    const float* Wv  = (const float*)d_in[6];
    const float* bv  = (const float*)d_in[7];
    const float* Wo  = (const float*)d_in[8];
    const float* bo  = (const float*)d_in[9];
    const float* W1  = (const float*)d_in[10];
    const float* b1  = (const float*)d_in[11];
    const float* W2  = (const float*)d_in[12];
    const float* b2  = (const float*)d_in[13];
    const float* g1  = (const float*)d_in[14];
    const float* be1 = (const float*)d_in[15];
    const float* g2  = (const float*)d_in[16];
    const float* be2 = (const float*)d_in[17];
    float* out = (float*)d_out;

    char* ws = (char*)d_ws;
    const size_t MB = 1ull << 20;
    // timeline-aliased layout, peak 184 MB:
    unsigned short* Xb   = (unsigned short*)(ws + 0);        // 16MB; dead after QKV
    unsigned short* Wqkv = (unsigned short*)(ws + 16 * MB);  // 6MB
    unsigned short* Wot  = (unsigned short*)(ws + 22 * MB);  // 2MB
    unsigned short* W1t  = (unsigned short*)(ws + 24 * MB);  // 8MB
    unsigned short* W2t  = (unsigned short*)(ws + 32 * MB);  // 8MB
    unsigned short* Qb   = (unsigned short*)(ws + 40 * MB);  // 16MB; dead after scores
    unsigned short* Kb   = (unsigned short*)(ws + 56 * MB);  // 16MB; dead after scores
    unsigned short* Vt   = (unsigned short*)(ws + 72 * MB);  // 16MB; dead after attnV
    unsigned short* Sc   = (unsigned short*)(ws + 88 * MB);  // 32MB bf16; dead after softmax
    unsigned short* Vb   = (unsigned short*)(ws + 152 * MB); // 16MB; dead after vtrans
    unsigned short* At   = (unsigned short*)(ws + 152 * MB); // 32MB (after Vb dead); dead after AV
    unsigned short* AVp  = (unsigned short*)(ws + 88 * MB);  // 2x16MB bf16 (reuse Sc)
    unsigned short* AVb  = (unsigned short*)(ws + 0);        // 16MB (reuse Xb)
    unsigned short* Op   = (unsigned short*)(ws + 152 * MB); // 2x16MB bf16 (reuse At)
    float*          Hf   = (float*)(ws + 40 * MB);           // 32MB (reuse Qb+Kb)
    unsigned short* Hb   = (unsigned short*)(ws + 72 * MB);  // 16MB (reuse Vt)
    unsigned short* F1   = (unsigned short*)(ws + 88 * MB);  // 64MB (reuse AVp + free)
    unsigned short* Fp   = (unsigned short*)(ws + 152 * MB); // 2x16MB bf16 (reuse Op)

    const dim3 blk(256);
    const dim3 blk512(512);
    const dim3 tblk(32, 8);
    const long long MN_d = (long long)B_ * S_ * D_;

    // input cast + ALL weight transposes (one launch)
    cast_bf16_kernel<<<dim3(8192), blk, 0, stream>>>(
        (const float4*)X, (ushort4*)Xb, B_ * S_ * D_ / 4);
    transpose_cast_all_kernel<<<dim3(12288), tblk, 0, stream>>>(
        Wq, Wk, Wv, Wo, W1, W2, Wqkv, Wot, W1t, W2t);

    // fused QKV: [8192,1024]@[3072,1024]^T, 384 blocks x 8 waves
    gemm_qkv<<<dim3(12, 32), blk512, 0, stream>>>(Xb, Wqkv, Qb, Kb, Vb, bq, bk, bv);

    // Vt[b][d][s] = transpose(Vb[b][s][d])
    vtrans_kernel<<<dim3(D_ / 64, S_ / 64, B_), blk, 0, stream>>>(Vb, Vt);

    // scores = Q @ K^T / 32 -> bf16, 256 blocks
    gemm_bt<1, 0, 0><<<dim3(8, 8, 4), blk512, 0, stream>>>(
        Qb, Kb, Sc, nullptr, S_, S_, D_, 0.03125f,
        (long long)S_ * D_, (long long)S_ * D_, (long long)S_ * S_);

    // attn = softmax(scores) + intensity  (bf16)
    softmax_bias_kernel<<<dim3(B_ * S_), blk, 0, stream>>>(Sc, inten, At);

    // AV split-K=2: bf16 partials, 256 blocks
    gemm_bt_sk<2><<<dim3(4, 8, 8), blk512, 0, stream>>>(
        At, Vt, AVp, S_, D_, S_ / 2, S_, S_,
        (long long)S_ * S_, (long long)D_ * S_);
    avred_kernel<<<dim3(8192), blk, 0, stream>>>(
        (const ushort4*)AVp, (const ushort4*)(AVp + MN_d), (ushort4*)AVb,
        (int)(MN_d / 4));

    // O-proj split-K=2: bf16 partials, 256 blocks
    gemm_bt_sk<2><<<dim3(4, 32, 2), blk512, 0, stream>>>(
        AVb, Wot, Op, B_ * S_, D_, D_ / 2, D_, D_, 0, 0);

    // h = LN(Op0 + Op1 + bo + X) -> Hf fp32 + Hb bf16
    ln_red_kernel<1><<<dim3(B_ * S_), blk, 0, stream>>>(
        Op, Op + MN_d, X, bo, g1, be1, Hf, Hb);

    // F1 = leaky_relu(h @ W1 + b1)  (bf16), 512 blocks
    gemm_bt<1, 1, 1><<<dim3(16, 32), blk512, 0, stream>>>(
        Hb, W1t, F1, b1, B_ * S_, DFF_, D_, 1.0f, 0, 0, 0);

    // ffn2 split-K=2: bf16 partials, 256 blocks
    gemm_bt_sk<2><<<dim3(4, 32, 2), blk512, 0, stream>>>(
        F1, W2t, Fp, B_ * S_, D_, DFF_ / 2, DFF_, DFF_, 0, 0);

    // out = LN(Fp0 + Fp1 + b2 + h)
    ln_red_kernel<0><<<dim3(B_ * S_), blk, 0, stream>>>(
        Fp, Fp + MN_d, Hf, b2, g2, be2, out, nullptr);
}